// Round 7
// baseline (459.177 us; speedup 1.0000x reference)
//
#include <hip/hip_runtime.h>
#include <math.h>

#define BATCH 128
#define NPRI  32768
#define NOBJ  20
#define THRSH 0.5f
#define VARNC 0.1f

// ---- workspace layout (~37 MB) ----
#define OFF_ACC   0                      // 3 doubles
#define OFF_DONE  48                     // int
#define OFF_NPOS  64                     // 128 ints -> 576
#define OFF_CNT   576                    // 128 ints -> 1088 (candidate counts)
#define OFF_BPK   2048                   // 2560 ull -> 22528
#define OFF_SEL   22528                  // uint sel[256]: [0..128)=T, [128..256)=Istar
#define OFF_HIST  32768                  // 128*1024 uint = 512 KB (zeroed by kA)
#define OFF_MATCH (1 << 20)              // 16 MB u32: (iou_bits & ~31) | best_truth_idx
#define OFF_CAND  (1 << 20)              // u16[128*32768] = 8 MB, ALIASES match (dead after kB)
#define OFF_LCPP  (17 << 20)             // 16 MB float
#define OFF_CONF  (33 << 20)             // 4 MB bytes
#define HDR_BYTES 24576

__device__ __forceinline__ float sl1(float d) {
    d = fabsf(d);
    return (d < 1.0f) ? 0.5f * d * d : d - 0.5f;
}
__device__ __forceinline__ float bce1(float x, bool hot) {
    float tgt = hot ? 0.925f : 0.025f;
    return fmaxf(x, 0.0f) - x * tgt + log1pf(expf(-fabsf(x)));
}

// ---- kA: one IoU sweep serving BOTH argmaxes; 8 priors/thread, 2048 blocks ----
__global__ __launch_bounds__(256) void kA(const float* __restrict__ targets,
                                          const float4* __restrict__ priors,
                                          unsigned long long* __restrict__ bpk,
                                          unsigned* __restrict__ match,
                                          unsigned* __restrict__ hist) {
    const int b = blockIdx.y, tid = threadIdx.x;
    if (tid < 64) hist[b * 1024 + blockIdx.x * 64 + tid] = 0;   // re-zero every launch
    const int base = blockIdx.x * 2048;

    float px0[8], py0[8], px1[8], py1[8], ab[8];
    #pragma unroll
    for (int it = 0; it < 8; ++it) {
        const float4 pr = priors[base + it * 256 + tid];
        px0[it] = pr.x - pr.z * 0.5f; py0[it] = pr.y - pr.w * 0.5f;
        px1[it] = pr.x + pr.z * 0.5f; py1[it] = pr.y + pr.w * 0.5f;
        ab[it] = (px1[it] - px0[it]) * (py1[it] - py0[it]);
    }
    float ppi[8], ppd[8]; int ppt[8];
    #pragma unroll
    for (int it = 0; it < 8; ++it) { ppi[it] = -1.0f; ppd[it] = 1.0f; ppt[it] = 0; }

    __shared__ unsigned long long skey[NOBJ];
    if (tid < NOBJ) skey[tid] = 0ull;
    __syncthreads();
    const int lane = tid & 63;
    const float* tb = targets + b * NOBJ * 6;

    #pragma unroll 1
    for (int o = 0; o < NOBJ; ++o) {
        const float t0 = tb[o * 6], t1 = tb[o * 6 + 1], t2 = tb[o * 6 + 2], t3 = tb[o * 6 + 3];
        const float aa = (t2 - t0) * (t3 - t1);
        float bi = -1.0f, bd = 1.0f; int bp = 0;
        #pragma unroll
        for (int it = 0; it < 8; ++it) {
            float ix = fminf(t2, px1[it]) - fmaxf(t0, px0[it]); ix = fmaxf(ix, 0.0f);
            float iy = fminf(t3, py1[it]) - fmaxf(t1, py0[it]); iy = fmaxf(iy, 0.0f);
            const float inter = ix * iy;
            const float den = aa + ab[it] - inter;
            // per-prior argmax over truths (min-o on ties: strict >, o ascending)
            if (inter * ppd[it] > ppi[it] * den) { ppi[it] = inter; ppd[it] = den; ppt[it] = o; }
            // per-truth argmax over priors (min-p on ties: strict >, p ascending in-thread)
            if (inter * bd > bi * den) { bi = inter; bd = den; bp = base + it * 256 + tid; }
        }
        const float iou = bi / bd;
        unsigned long long key = ((unsigned long long)__float_as_uint(iou) << 32)
                               | (unsigned long long)(0xFFFFFFFFu - (unsigned)bp);
        #pragma unroll
        for (int s = 32; s > 0; s >>= 1) {
            unsigned long long k2 = __shfl_xor(key, s, 64);
            if (k2 > key) key = k2;
        }
        if (lane == 0) atomicMax(&skey[o], key);
    }
    #pragma unroll
    for (int it = 0; it < 8; ++it) {
        const float iou = ppi[it] / ppd[it];              // same div order as reference
        match[(size_t)b * NPRI + base + it * 256 + tid] =
            (__float_as_uint(iou) & 0xFFFFFFE0u) | (unsigned)ppt[it];
    }
    __syncthreads();
    if (tid < NOBJ) atomicMax(&bpk[b * NOBJ + tid], skey[tid]);
}

// ---- kB: read match, override, lse/losses, lcpp/confb, 1024-bin hist ----
__global__ __launch_bounds__(256) void kB(const float* __restrict__ targets,
                                          const float4* __restrict__ priors,
                                          const float2* __restrict__ loc,
                                          const float4* __restrict__ cnf,
                                          const float* __restrict__ reg,
                                          const unsigned long long* __restrict__ bpk,
                                          const unsigned* __restrict__ match,
                                          float* __restrict__ lcpp,
                                          unsigned char* __restrict__ confb,
                                          unsigned* __restrict__ hist,
                                          double* __restrict__ acc,
                                          int* __restrict__ npos) {
    const int b = blockIdx.y, tid = threadIdx.x;
    const int base = blockIdx.x * 1024;
    const float* tb = targets + b * NOBJ * 6;            // block-uniform -> s_loads
    const unsigned long long* bb = bpk + b * NOBJ;
    __shared__ unsigned lh[1024];
    lh[tid] = 0; lh[tid + 256] = 0; lh[tid + 512] = 0; lh[tid + 768] = 0;

    unsigned mu[4]; float4 x[4];
    #pragma unroll
    for (int j = 0; j < 4; ++j) mu[j] = match[(size_t)b * NPRI + base + j * 256 + tid];
    #pragma unroll
    for (int j = 0; j < 4; ++j) x[j] = cnf[(size_t)b * NPRI + base + j * 256 + tid];

    float bto[4]; int bt[4];
    #pragma unroll
    for (int j = 0; j < 4; ++j) {
        bto[j] = __uint_as_float(mu[j] & 0xFFFFFFE0u);
        bt[j] = (int)(mu[j] & 31u);
    }
    #pragma unroll
    for (int o = 0; o < NOBJ; ++o) {                     // serial scatter override, last o wins
        const int bpi = (int)(0xFFFFFFFFu - (unsigned)(bb[o] & 0xFFFFFFFFull));
        #pragma unroll
        for (int j = 0; j < 4; ++j)
            if (bpi == base + j * 256 + tid) { bto[j] = 2.0f; bt[j] = o; }
    }
    __syncthreads();                                      // lh zero visible before atomics

    float ll = 0.0f, lr = 0.0f; int np = 0;
    #pragma unroll
    for (int j = 0; j < 4; ++j) {
        const int p = base + j * 256 + tid;
        const float* ts = tb + bt[j] * 6;
        int c = 0;
        if (bto[j] >= THRSH) c = (int)ts[4];
        const float m = fmaxf(fmaxf(x[j].x, x[j].y), fmaxf(x[j].z, x[j].w));
        const float lse = m + logf(expf(x[j].x - m) + expf(x[j].y - m) +
                                   expf(x[j].z - m) + expf(x[j].w - m));
        const float picked = (c == 0) ? x[j].x : (c == 1) ? x[j].y : (c == 2) ? x[j].z : x[j].w;
        const float lval = (c > 0) ? 0.0f : (lse - picked);
        lcpp[(size_t)b * NPRI + p] = lval;
        confb[(size_t)b * NPRI + p] = (unsigned char)c;
        atomicAdd(&lh[__float_as_uint(lval) >> 21], 1u);  // sign=0 -> bin < 1024
        if (c > 0) {
            const float4 pr = priors[p];
            const float cx = (ts[0] + ts[2]) * 0.5f, cy = (ts[1] + ts[3]) * 0.5f;
            const float lt0 = (cx - pr.x) / (VARNC * pr.z);
            const float lt1 = (cy - pr.y) / (VARNC * pr.w);
            const float2 ld = loc[(size_t)b * NPRI + p];
            ll += sl1(ld.x - lt0) + sl1(ld.y - lt1);
            lr += sl1(reg[(size_t)b * NPRI + p] - ts[5]);
            ++np;
        }
    }
    #pragma unroll
    for (int s = 32; s > 0; s >>= 1) {
        ll += __shfl_down(ll, s, 64);
        lr += __shfl_down(lr, s, 64);
        np += __shfl_down(np, s, 64);
    }
    __shared__ float sred[4][2];
    __shared__ int sredn[4];
    const int lane = tid & 63, w = tid >> 6;
    if (lane == 0) { sred[w][0] = ll; sred[w][1] = lr; sredn[w] = np; }
    __syncthreads();                                      // covers lh atomics + sred
    #pragma unroll
    for (int q = 0; q < 4; ++q) {                         // flush sparse hist
        const unsigned v = lh[tid + q * 256];
        if (v) atomicAdd(&hist[b * 1024 + tid + q * 256], v);
    }
    if (tid == 0) {
        const float tl = sred[0][0] + sred[1][0] + sred[2][0] + sred[3][0];
        const float tr = sred[0][1] + sred[1][1] + sred[2][1] + sred[3][1];
        const int tn = sredn[0] + sredn[1] + sredn[2] + sredn[3];
        if (tn) {
            atomicAdd(&acc[0], (double)tl);
            atomicAdd(&acc[2], (double)tr);
            atomicAdd(&npos[b], tn);
        }
    }
}

// ---- kR2 (wide): derive B1 from hist, compact B1-bin candidate indices ----
__global__ __launch_bounds__(256) void kR2(const float* __restrict__ lcpp,
                                           const unsigned* __restrict__ hist,
                                           const int* __restrict__ npos,
                                           unsigned short* __restrict__ cand,
                                           int* __restrict__ cnt) {
    const int b = blockIdx.y, tid = threadIdx.x, lane = tid & 63, w = tid >> 6;
    __shared__ unsigned wtot[4];
    __shared__ int resB;
    int k = min(3 * npos[b], NPRI - 1); if (k < 1) k = 1;
    const unsigned r1 = (unsigned)k;                      // rank r = k-1, need suffix >= r+1 = k
    const unsigned h0 = hist[b * 1024 + 4 * tid],     h1 = hist[b * 1024 + 4 * tid + 1],
                   h2 = hist[b * 1024 + 4 * tid + 2], h3 = hist[b * 1024 + 4 * tid + 3];
    const unsigned sv = h0 + h1 + h2 + h3;
    unsigned s = sv;
    #pragma unroll
    for (int d = 1; d < 64; d <<= 1) { const unsigned t = __shfl_down(s, d, 64); if (lane + d < 64) s += t; }
    if (lane == 0) wtot[w] = s;
    __syncthreads();
    unsigned add = 0;
    #pragma unroll
    for (int q = 0; q < 4; ++q) if (q > w) add += wtot[q];
    const unsigned suf = s + add;                         // suffix(4*tid)
    if (suf >= r1 && suf - h0 < r1) resB = 4 * tid;
    if (suf - h0 >= r1 && suf - h0 - h1 < r1) resB = 4 * tid + 1;
    if (suf - h0 - h1 >= r1 && suf - h0 - h1 - h2 < r1) resB = 4 * tid + 2;
    if (suf - h0 - h1 - h2 >= r1 && suf - sv < r1) resB = 4 * tid + 3;
    __syncthreads();
    const unsigned B1 = (unsigned)resB;

    const float4* v4 = (const float4*)(lcpp + (size_t)b * NPRI);
    const int base4 = blockIdx.x * 1024;                  // 8 x-blocks x 1024 float4
    for (int it = 0; it < 4; ++it) {
        const float4 xx = v4[base4 + it * 256 + tid];
        const int i0 = 4 * (base4 + it * 256 + tid);
        const unsigned u0 = __float_as_uint(xx.x), u1 = __float_as_uint(xx.y);
        const unsigned u2 = __float_as_uint(xx.z), u3 = __float_as_uint(xx.w);
        if ((u0 >> 21) == B1) { const int p = atomicAdd(&cnt[b], 1); cand[(size_t)b * NPRI + p] = (unsigned short)i0; }
        if ((u1 >> 21) == B1) { const int p = atomicAdd(&cnt[b], 1); cand[(size_t)b * NPRI + p] = (unsigned short)(i0 + 1); }
        if ((u2 >> 21) == B1) { const int p = atomicAdd(&cnt[b], 1); cand[(size_t)b * NPRI + p] = (unsigned short)(i0 + 2); }
        if ((u3 >> 21) == B1) { const int p = atomicAdd(&cnt[b], 1); cand[(size_t)b * NPRI + p] = (unsigned short)(i0 + 3); }
    }
}

// ---- kR3 (tiny): exact T + tie cutoff among candidates only ----
__global__ __launch_bounds__(1024) void kR3(const float* __restrict__ lcpp,
                                            const unsigned* __restrict__ hist,
                                            const int* __restrict__ npos,
                                            const unsigned short* __restrict__ cand,
                                            const int* __restrict__ cnt,
                                            unsigned* __restrict__ sel) {
    const int b = blockIdx.x, tid = threadIdx.x, lane = tid & 63, w = tid >> 6;
    __shared__ unsigned h[2048];
    __shared__ unsigned wtot[16];
    __shared__ int res[2];
    __shared__ int sIstar;
    const float* v = lcpp + (size_t)b * NPRI;
    const unsigned short* cd = cand + (size_t)b * NPRI;
    int k = min(3 * npos[b], NPRI - 1); if (k < 1) k = 1;
    int r = k - 1;

    // level 0: 1024-bin precomputed hist
    {
        const unsigned a = hist[b * 1024 + tid];
        unsigned s = a;
        #pragma unroll
        for (int d = 1; d < 64; d <<= 1) { const unsigned t = __shfl_down(s, d, 64); if (lane + d < 64) s += t; }
        if (lane == 0) wtot[w] = s;
        __syncthreads();
        unsigned add = 0;
        #pragma unroll
        for (int q = 0; q < 16; ++q) if (q > w) add += wtot[q];
        const unsigned Sincl = s + add;
        if (Sincl >= (unsigned)(r + 1) && Sincl - a < (unsigned)(r + 1)) { res[0] = tid; res[1] = r - (int)(Sincl - a); }
        __syncthreads();
    }
    const unsigned B1 = (unsigned)res[0];
    r = res[1];
    const int n = cnt[b];
    __syncthreads();

    // level 1: bits[20:10] among candidates
    h[tid] = 0; h[tid + 1024] = 0;
    __syncthreads();
    for (int i = tid; i < n; i += 1024)
        atomicAdd(&h[(__float_as_uint(v[cd[i]]) >> 10) & 2047u], 1u);
    __syncthreads();
    {
        const unsigned a = h[2 * tid], b2 = h[2 * tid + 1];
        const unsigned sv = a + b2;
        unsigned s = sv;
        #pragma unroll
        for (int d = 1; d < 64; d <<= 1) { const unsigned t = __shfl_down(s, d, 64); if (lane + d < 64) s += t; }
        if (lane == 0) wtot[w] = s;
        __syncthreads();
        unsigned add = 0;
        #pragma unroll
        for (int q = 0; q < 16; ++q) if (q > w) add += wtot[q];
        const unsigned Sincl = s + add;
        const unsigned r1 = (unsigned)(r + 1);
        if (Sincl >= r1 && Sincl - a < r1) { res[0] = 2 * tid; res[1] = r - (int)(Sincl - a); }
        if (Sincl - a >= r1 && Sincl - sv < r1) { res[0] = 2 * tid + 1; res[1] = r - (int)(Sincl - sv); }
        __syncthreads();
    }
    const unsigned P22 = (B1 << 11) | (unsigned)res[0];
    r = res[1];
    __syncthreads();

    // level 2: bits[9:0] among candidates
    h[tid] = 0;
    __syncthreads();
    for (int i = tid; i < n; i += 1024) {
        const unsigned u = __float_as_uint(v[cd[i]]);
        if ((u >> 10) == P22) atomicAdd(&h[u & 1023u], 1u);
    }
    __syncthreads();
    {
        const unsigned a = h[tid];
        unsigned s = a;
        #pragma unroll
        for (int d = 1; d < 64; d <<= 1) { const unsigned t = __shfl_down(s, d, 64); if (lane + d < 64) s += t; }
        if (lane == 0) wtot[w] = s;
        __syncthreads();
        unsigned add = 0;
        #pragma unroll
        for (int q = 0; q < 16; ++q) if (q > w) add += wtot[q];
        const unsigned Sincl = s + add;
        if (Sincl >= (unsigned)(r + 1) && Sincl - a < (unsigned)(r + 1)) { res[0] = tid; res[1] = r - (int)(Sincl - a); }
        __syncthreads();
    }
    const unsigned T = (P22 << 10) | (unsigned)res[0];
    const int eq = (int)h[res[0]];
    const int rem = res[1] + 1;                           // ties to accept (stable, low index first)

    int Istar = 0x7FFFFFFF;
    if (eq > rem) {                                       // rare path (dead on this data)
        if (tid == 0) sIstar = 0x7FFFFFFF;
        __syncthreads();
        for (int i = tid; i < n; i += 1024) {
            const int idx = cd[i];
            if (__float_as_uint(v[idx]) != T) continue;
            int rank = 0;
            for (int j = 0; j < n; ++j) {
                const int jdx = cd[j];
                if (jdx < idx && __float_as_uint(v[jdx]) == T) ++rank;
            }
            if (rank == rem - 1) sIstar = idx;
        }
        __syncthreads();
        Istar = sIstar;
    }
    if (tid == 0) { sel[b] = T; sel[128 + b] = (unsigned)Istar; }
}

// ---- kBCE (wide): selection predicate + BCE + finalize ----
__global__ __launch_bounds__(256) void kBCE(const float* __restrict__ lcpp,
                                            const unsigned char* __restrict__ confb,
                                            const float4* __restrict__ cnf,
                                            const unsigned* __restrict__ sel,
                                            const int* __restrict__ npos,
                                            double* __restrict__ acc,
                                            int* __restrict__ done,
                                            float* __restrict__ out) {
    const int b = blockIdx.y, tid = threadIdx.x;
    const unsigned T = sel[b];
    const int Istar = (int)sel[128 + b];
    const int e0 = (blockIdx.x * 256 + tid) * 8;          // grid.x=16 covers 32768
    const float4* v4 = (const float4*)(lcpp + (size_t)b * NPRI);
    const float4 va = v4[e0 / 4], vb = v4[e0 / 4 + 1];
    const uchar4 ca = *(const uchar4*)(confb + (size_t)b * NPRI + e0);
    const uchar4 cb4 = *(const uchar4*)(confb + (size_t)b * NPRI + e0 + 4);
    const float vv[8] = {va.x, va.y, va.z, va.w, vb.x, vb.y, vb.z, vb.w};
    const int cc[8] = {ca.x, ca.y, ca.z, ca.w, cb4.x, cb4.y, cb4.z, cb4.w};
    float local = 0.0f;
    #pragma unroll
    for (int e = 0; e < 8; ++e) {
        const int i = e0 + e;
        const unsigned u = __float_as_uint(vv[e]);
        const int c = cc[e];
        if (c > 0 || u > T || (u == T && i <= Istar)) {
            const float4 xx = cnf[(size_t)b * NPRI + i];
            local += bce1(xx.x, c == 0) + bce1(xx.y, c == 1) + bce1(xx.z, c == 2) + bce1(xx.w, c == 3);
        }
    }
    #pragma unroll
    for (int s = 32; s > 0; s >>= 1) local += __shfl_down(local, s, 64);
    __shared__ float sc[4];
    const int lane = tid & 63, w = tid >> 6;
    if (lane == 0) sc[w] = local;
    __syncthreads();
    __shared__ bool slast;
    if (tid == 0) {
        atomicAdd(&acc[1], (double)(sc[0] + sc[1] + sc[2] + sc[3]));
        __threadfence();
        const int old = atomicAdd(done, 1);
        slast = (old == 16 * BATCH - 1);
    }
    __syncthreads();
    if (slast && tid == 0) {
        __threadfence();
        int n = 0;
        for (int q = 0; q < BATCH; ++q) n += npos[q];
        const double a0 = atomicAdd(&acc[0], 0.0);        // atomic-RMW read: cross-XCD safe
        const double a1 = atomicAdd(&acc[1], 0.0);
        const double a2 = atomicAdd(&acc[2], 0.0);
        const double N = (double)n;
        out[0] = (float)(a0 / N);
        out[1] = (float)(a1 / N);
        out[2] = (float)(a2 / N);
    }
}

extern "C" void kernel_launch(void* const* d_in, const int* in_sizes, int n_in,
                              void* d_out, int out_size, void* d_ws, size_t ws_size,
                              hipStream_t stream) {
    const float* loc = (const float*)d_in[0];
    const float* cnfp = (const float*)d_in[1];
    const float* regp = (const float*)d_in[2];
    const float* tgt = (const float*)d_in[3];
    const float* pri = (const float*)d_in[4];

    char* ws = (char*)d_ws;
    double* acc = (double*)(ws + OFF_ACC);
    int* done = (int*)(ws + OFF_DONE);
    int* npos = (int*)(ws + OFF_NPOS);
    int* cnt = (int*)(ws + OFF_CNT);
    unsigned long long* bpk = (unsigned long long*)(ws + OFF_BPK);
    unsigned* sel = (unsigned*)(ws + OFF_SEL);
    unsigned* hist = (unsigned*)(ws + OFF_HIST);
    unsigned* match = (unsigned*)(ws + OFF_MATCH);
    unsigned short* cand = (unsigned short*)(ws + OFF_CAND);
    float* lcpp = (float*)(ws + OFF_LCPP);
    unsigned char* confb = (unsigned char*)(ws + OFF_CONF);

    hipMemsetAsync(ws, 0, HDR_BYTES, stream);   // acc/done/npos/cnt/bpk/sel (hist zeroed by kA)

    kA<<<dim3(16, BATCH), 256, 0, stream>>>(tgt, (const float4*)pri, bpk, match, hist);
    kB<<<dim3(32, BATCH), 256, 0, stream>>>(tgt, (const float4*)pri, (const float2*)loc,
                                            (const float4*)cnfp, regp, bpk, match,
                                            lcpp, confb, hist, acc, npos);
    kR2<<<dim3(8, BATCH), 256, 0, stream>>>(lcpp, hist, npos, cand, cnt);
    kR3<<<BATCH, 1024, 0, stream>>>(lcpp, hist, npos, cand, cnt, sel);
    kBCE<<<dim3(16, BATCH), 256, 0, stream>>>(lcpp, confb, (const float4*)cnfp, sel, npos,
                                              acc, done, (float*)d_out);
}

// Round 8
// 373.040 us; speedup vs baseline: 1.2309x; 1.2309x over previous
//
#include <hip/hip_runtime.h>
#include <math.h>

#define BATCH 128
#define NPRI  32768
#define NOBJ  20
#define OGRP  5
#define THRSH 0.5f
#define VARNC 0.1f

// ---- workspace layout (~37 MB) ----
#define OFF_ACC   0                      // 3 doubles
#define OFF_DONE  48                     // int
#define OFF_NPOS  64                     // 128 ints
#define OFF_CNT   576                    // 128 ints (candidate counts)
#define OFF_BPK   2048                   // 2560 ull
#define OFF_SEL   22528                  // uint sel[256]: [0..128)=T, [128..256)=Istar
#define OFF_HIST  32768                  // 128*1024 uint = 512 KB (zeroed by kMatch)
#define OFF_MATCH (1 << 20)              // 16 MB u32: (iou_bits & ~31) | best_truth_idx
#define OFF_CAND  (1 << 20)              // u32 values, ALIASES match (dead after kB)
#define OFF_LCPP  (17 << 20)             // 16 MB float
#define OFF_CONF  (33 << 20)             // 4 MB bytes
#define HDR_BYTES 24576

__device__ __forceinline__ float sl1(float d) {
    d = fabsf(d);
    return (d < 1.0f) ? 0.5f * d * d : d - 0.5f;
}
__device__ __forceinline__ float bce1(float x, bool hot) {
    float tgt = hot ? 0.925f : 0.025f;
    return fmaxf(x, 0.0f) - x * tgt + log1pf(expf(-fabsf(x)));
}
// wave-aggregated LDS histogram add: ~#distinct-bins atomics instead of 64
__device__ __forceinline__ void waveAgg(unsigned int* h, unsigned bin, int lane) {
    unsigned long long todo = __ballot(1);
    while (todo) {
        const int leader = __builtin_ctzll(todo);
        const unsigned lb = (unsigned)__shfl((int)bin, leader, 64);
        const unsigned long long m = __ballot(bin == lb);
        if (lane == leader) atomicAdd(&h[lb], (unsigned)__popcll(m));
        todo &= ~m;
    }
}

// ---- kMatch: blockIdx.x<4 -> per-truth argmax (5 truths/block); else per-prior sweep ----
__global__ __launch_bounds__(256) void kMatch(const float* __restrict__ targets,
                                              const float4* __restrict__ priors,
                                              unsigned long long* __restrict__ bpk,
                                              unsigned* __restrict__ match,
                                              unsigned* __restrict__ hist) {
    const int b = blockIdx.y, tid = threadIdx.x, lane = tid & 63;
    const float* tb = targets + b * NOBJ * 6;

    if (blockIdx.x < 4) {
        // ---- per-truth best prior: block owns truths og..og+4, threads stride priors ----
        const int og = blockIdx.x * OGRP;
        float t0[OGRP], t1[OGRP], t2[OGRP], t3[OGRP], aa[OGRP];
        #pragma unroll
        for (int oo = 0; oo < OGRP; ++oo) {
            const float* t = tb + (og + oo) * 6;
            t0[oo] = t[0]; t1[oo] = t[1]; t2[oo] = t[2]; t3[oo] = t[3];
            aa[oo] = (t2[oo] - t0[oo]) * (t3[oo] - t1[oo]);
        }
        float bi[OGRP], bd[OGRP]; int bp[OGRP];
        #pragma unroll
        for (int oo = 0; oo < OGRP; ++oo) { bi[oo] = -1.0f; bd[oo] = 1.0f; bp[oo] = 0; }
        #pragma unroll 4
        for (int s = 0; s < 128; ++s) {
            const int p = s * 256 + tid;                  // ascending p within thread
            const float4 pr = priors[p];
            const float px0 = pr.x - pr.z * 0.5f, py0 = pr.y - pr.w * 0.5f;
            const float px1 = pr.x + pr.z * 0.5f, py1 = pr.y + pr.w * 0.5f;
            const float ab = (px1 - px0) * (py1 - py0);
            #pragma unroll
            for (int oo = 0; oo < OGRP; ++oo) {
                float ix = fminf(t2[oo], px1) - fmaxf(t0[oo], px0); ix = fmaxf(ix, 0.0f);
                float iy = fminf(t3[oo], py1) - fmaxf(t1[oo], py0); iy = fmaxf(iy, 0.0f);
                const float inter = ix * iy;
                const float den = aa[oo] + ab - inter;
                if (inter * bd[oo] > bi[oo] * den) { bi[oo] = inter; bd[oo] = den; bp[oo] = p; }
            }
        }
        __shared__ unsigned long long red[OGRP];
        if (tid < OGRP) red[tid] = 0ull;
        __syncthreads();
        #pragma unroll
        for (int oo = 0; oo < OGRP; ++oo) {
            const float iou = bi[oo] / bd[oo];
            unsigned long long key = ((unsigned long long)__float_as_uint(iou) << 32)
                                   | (unsigned long long)(0xFFFFFFFFu - (unsigned)bp[oo]);
            #pragma unroll
            for (int s = 32; s > 0; s >>= 1) {
                unsigned long long k2 = __shfl_xor(key, s, 64);
                if (k2 > key) key = k2;
            }
            if (lane == 0) atomicMax(&red[oo], key);
        }
        __syncthreads();
        if (tid < OGRP) bpk[b * NOBJ + og + tid] = red[tid];   // sole owner: plain store
    } else {
        // ---- per-prior sweep: 8 priors/thread, pure streaming, no cross-lane ops ----
        const int xb = blockIdx.x - 4;                    // 0..15
        if (tid < 64) hist[b * 1024 + xb * 64 + tid] = 0; // re-zero hist every launch
        const int base = xb * 2048;
        float px0[8], py0[8], px1[8], py1[8], ab[8];
        #pragma unroll
        for (int it = 0; it < 8; ++it) {
            const float4 pr = priors[base + it * 256 + tid];
            px0[it] = pr.x - pr.z * 0.5f; py0[it] = pr.y - pr.w * 0.5f;
            px1[it] = pr.x + pr.z * 0.5f; py1[it] = pr.y + pr.w * 0.5f;
            ab[it] = (px1[it] - px0[it]) * (py1[it] - py0[it]);
        }
        float ppi[8], ppd[8]; int ppt[8];
        #pragma unroll
        for (int it = 0; it < 8; ++it) { ppi[it] = -1.0f; ppd[it] = 1.0f; ppt[it] = 0; }
        #pragma unroll 4
        for (int o = 0; o < NOBJ; ++o) {
            const float t0 = tb[o * 6], t1 = tb[o * 6 + 1], t2 = tb[o * 6 + 2], t3 = tb[o * 6 + 3];
            const float aa = (t2 - t0) * (t3 - t1);
            #pragma unroll
            for (int it = 0; it < 8; ++it) {
                float ix = fminf(t2, px1[it]) - fmaxf(t0, px0[it]); ix = fmaxf(ix, 0.0f);
                float iy = fminf(t3, py1[it]) - fmaxf(t1, py0[it]); iy = fmaxf(iy, 0.0f);
                const float inter = ix * iy;
                const float den = aa + ab[it] - inter;
                if (inter * ppd[it] > ppi[it] * den) { ppi[it] = inter; ppd[it] = den; ppt[it] = o; }
            }
        }
        #pragma unroll
        for (int it = 0; it < 8; ++it) {
            const float iou = ppi[it] / ppd[it];          // same div order as reference
            match[(size_t)b * NPRI + base + it * 256 + tid] =
                (__float_as_uint(iou) & 0xFFFFFFE0u) | (unsigned)ppt[it];
        }
    }
}

// ---- kB: 8 priors/thread; match+override, lse/losses, lcpp/confb, waveAgg hist ----
__global__ __launch_bounds__(256) void kB(const float* __restrict__ targets,
                                          const float4* __restrict__ priors,
                                          const float2* __restrict__ loc,
                                          const float4* __restrict__ cnf,
                                          const float* __restrict__ reg,
                                          const unsigned long long* __restrict__ bpk,
                                          const unsigned* __restrict__ match,
                                          float* __restrict__ lcpp,
                                          unsigned char* __restrict__ confb,
                                          unsigned* __restrict__ hist,
                                          double* __restrict__ acc,
                                          int* __restrict__ npos) {
    const int b = blockIdx.y, tid = threadIdx.x;
    const int base = blockIdx.x * 2048;
    const float* tb = targets + b * NOBJ * 6;            // block-uniform -> s_loads
    const unsigned long long* bb = bpk + b * NOBJ;
    __shared__ unsigned lh[1024];
    lh[tid] = 0; lh[tid + 256] = 0; lh[tid + 512] = 0; lh[tid + 768] = 0;

    unsigned mu[8]; float4 x[8];
    #pragma unroll
    for (int j = 0; j < 8; ++j) mu[j] = match[(size_t)b * NPRI + base + j * 256 + tid];
    #pragma unroll
    for (int j = 0; j < 8; ++j) x[j] = cnf[(size_t)b * NPRI + base + j * 256 + tid];

    float bto[8]; int bt[8];
    #pragma unroll
    for (int j = 0; j < 8; ++j) {
        bto[j] = __uint_as_float(mu[j] & 0xFFFFFFE0u);
        bt[j] = (int)(mu[j] & 31u);
    }
    #pragma unroll
    for (int o = 0; o < NOBJ; ++o) {                     // serial scatter override, last o wins
        const int bpi = (int)(0xFFFFFFFFu - (unsigned)(bb[o] & 0xFFFFFFFFull));
        #pragma unroll
        for (int j = 0; j < 8; ++j)
            if (bpi == base + j * 256 + tid) { bto[j] = 2.0f; bt[j] = o; }
    }
    __syncthreads();                                      // lh zero visible before atomics

    const int lane = tid & 63, w = tid >> 6;
    float ll = 0.0f, lr = 0.0f; int np = 0;
    #pragma unroll
    for (int j = 0; j < 8; ++j) {
        const int p = base + j * 256 + tid;
        const float* ts = tb + bt[j] * 6;
        int c = 0;
        if (bto[j] >= THRSH) c = (int)ts[4];
        const float m = fmaxf(fmaxf(x[j].x, x[j].y), fmaxf(x[j].z, x[j].w));
        const float lse = m + logf(expf(x[j].x - m) + expf(x[j].y - m) +
                                   expf(x[j].z - m) + expf(x[j].w - m));
        const float picked = (c == 0) ? x[j].x : (c == 1) ? x[j].y : (c == 2) ? x[j].z : x[j].w;
        const float lval = (c > 0) ? 0.0f : (lse - picked);
        lcpp[(size_t)b * NPRI + p] = lval;
        confb[(size_t)b * NPRI + p] = (unsigned char)c;
        waveAgg(lh, __float_as_uint(lval) >> 21, lane);   // aggregated: no same-addr serialize
        if (c > 0) {
            const float4 pr = priors[p];
            const float cx = (ts[0] + ts[2]) * 0.5f, cy = (ts[1] + ts[3]) * 0.5f;
            const float lt0 = (cx - pr.x) / (VARNC * pr.z);
            const float lt1 = (cy - pr.y) / (VARNC * pr.w);
            const float2 ld = loc[(size_t)b * NPRI + p];
            ll += sl1(ld.x - lt0) + sl1(ld.y - lt1);
            lr += sl1(reg[(size_t)b * NPRI + p] - ts[5]);
            ++np;
        }
    }
    #pragma unroll
    for (int s = 32; s > 0; s >>= 1) {
        ll += __shfl_down(ll, s, 64);
        lr += __shfl_down(lr, s, 64);
        np += __shfl_down(np, s, 64);
    }
    __shared__ float sred[4][2];
    __shared__ int sredn[4];
    if (lane == 0) { sred[w][0] = ll; sred[w][1] = lr; sredn[w] = np; }
    __syncthreads();                                      // covers lh atomics + sred
    #pragma unroll
    for (int q = 0; q < 4; ++q) {                         // sparse flush
        const unsigned v = lh[tid + q * 256];
        if (v) atomicAdd(&hist[b * 1024 + tid + q * 256], v);
    }
    if (tid == 0) {
        const float tl = sred[0][0] + sred[1][0] + sred[2][0] + sred[3][0];
        const float tr = sred[0][1] + sred[1][1] + sred[2][1] + sred[3][1];
        const int tn = sredn[0] + sredn[1] + sredn[2] + sredn[3];
        if (tn) {
            atomicAdd(&acc[0], (double)tl);
            atomicAdd(&acc[2], (double)tr);
            atomicAdd(&npos[b], tn);
        }
    }
}

// ---- kR2: derive B1, block-aggregated compaction of B1-member VALUES ----
__global__ __launch_bounds__(256) void kR2(const float* __restrict__ lcpp,
                                           const unsigned* __restrict__ hist,
                                           const int* __restrict__ npos,
                                           unsigned* __restrict__ cand,
                                           int* __restrict__ cnt) {
    const int b = blockIdx.y, tid = threadIdx.x, lane = tid & 63, w = tid >> 6;
    __shared__ unsigned wtot[4];
    __shared__ int resB;
    int k = min(3 * npos[b], NPRI - 1); if (k < 1) k = 1;
    const unsigned r1 = (unsigned)k;
    const unsigned h0 = hist[b * 1024 + 4 * tid],     h1 = hist[b * 1024 + 4 * tid + 1],
                   h2 = hist[b * 1024 + 4 * tid + 2], h3 = hist[b * 1024 + 4 * tid + 3];
    const unsigned sv = h0 + h1 + h2 + h3;
    unsigned s = sv;
    #pragma unroll
    for (int d = 1; d < 64; d <<= 1) { const unsigned t = __shfl_down(s, d, 64); if (lane + d < 64) s += t; }
    if (lane == 0) wtot[w] = s;
    __syncthreads();
    unsigned add = 0;
    #pragma unroll
    for (int q = 0; q < 4; ++q) if (q > w) add += wtot[q];
    const unsigned suf = s + add;
    if (suf >= r1 && suf - h0 < r1) resB = 4 * tid;
    if (suf - h0 >= r1 && suf - h0 - h1 < r1) resB = 4 * tid + 1;
    if (suf - h0 - h1 >= r1 && suf - h0 - h1 - h2 < r1) resB = 4 * tid + 2;
    if (suf - h0 - h1 - h2 >= r1 && suf - sv < r1) resB = 4 * tid + 3;
    __syncthreads();
    const unsigned B1 = (unsigned)resB;

    const float4* v4 = (const float4*)(lcpp + (size_t)b * NPRI);
    const int base4 = blockIdx.x * 1024;
    float4 xx[4];
    #pragma unroll
    for (int it = 0; it < 4; ++it) xx[it] = v4[base4 + it * 256 + tid];
    const float* xe = (const float*)xx;
    int myc = 0;
    #pragma unroll
    for (int e = 0; e < 16; ++e) myc += ((__float_as_uint(xe[e]) >> 21) == B1);
    // block-exclusive scan of per-thread counts, ONE atomic per block
    int inc = myc;
    #pragma unroll
    for (int d = 1; d < 64; d <<= 1) { const int t = __shfl_up(inc, d, 64); if (lane >= d) inc += t; }
    __shared__ int wt[4];
    __shared__ int sbase;
    if (lane == 63) wt[w] = inc;
    __syncthreads();
    int woff = 0;
    #pragma unroll
    for (int q = 0; q < 4; ++q) if (q < w) woff += wt[q];
    if (tid == 0) sbase = atomicAdd(&cnt[b], wt[0] + wt[1] + wt[2] + wt[3]);
    __syncthreads();
    int pos = sbase + woff + inc - myc;
    unsigned* cb = cand + (size_t)b * NPRI;
    #pragma unroll
    for (int e = 0; e < 16; ++e) {
        const unsigned u = __float_as_uint(xe[e]);
        if ((u >> 21) == B1) cb[pos++] = u;
    }
}

// ---- kR3 (tiny): exact T + tie cutoff among candidate VALUES ----
__global__ __launch_bounds__(1024) void kR3(const float* __restrict__ lcpp,
                                            const unsigned* __restrict__ hist,
                                            const int* __restrict__ npos,
                                            const unsigned* __restrict__ cand,
                                            const int* __restrict__ cnt,
                                            unsigned* __restrict__ sel) {
    const int b = blockIdx.x, tid = threadIdx.x, lane = tid & 63, w = tid >> 6;
    __shared__ unsigned h[2048];
    __shared__ unsigned wtot[16];
    __shared__ int res[2];
    __shared__ int wsum[16];
    __shared__ int srun, sIstar;
    int k = min(3 * npos[b], NPRI - 1); if (k < 1) k = 1;
    int r = k - 1;

    // level 0: precomputed 1024-bin hist
    {
        const unsigned a = hist[b * 1024 + tid];
        unsigned s = a;
        #pragma unroll
        for (int d = 1; d < 64; d <<= 1) { const unsigned t = __shfl_down(s, d, 64); if (lane + d < 64) s += t; }
        if (lane == 0) wtot[w] = s;
        __syncthreads();
        unsigned add = 0;
        #pragma unroll
        for (int q = 0; q < 16; ++q) if (q > w) add += wtot[q];
        const unsigned Sincl = s + add;
        if (Sincl >= (unsigned)(r + 1) && Sincl - a < (unsigned)(r + 1)) { res[0] = tid; res[1] = r - (int)(Sincl - a); }
        __syncthreads();
    }
    r = res[1];
    const int n = cnt[b];
    const unsigned* cd = cand + (size_t)b * NPRI;
    __syncthreads();

    // level 1: bits[20:10] among candidates (all are B1-members)
    h[tid] = 0; h[tid + 1024] = 0;
    __syncthreads();
    for (int i = tid; i < n; i += 1024)
        atomicAdd(&h[(cd[i] >> 10) & 2047u], 1u);
    __syncthreads();
    {
        const unsigned a = h[2 * tid], b2 = h[2 * tid + 1];
        const unsigned sv = a + b2;
        unsigned s = sv;
        #pragma unroll
        for (int d = 1; d < 64; d <<= 1) { const unsigned t = __shfl_down(s, d, 64); if (lane + d < 64) s += t; }
        if (lane == 0) wtot[w] = s;
        __syncthreads();
        unsigned add = 0;
        #pragma unroll
        for (int q = 0; q < 16; ++q) if (q > w) add += wtot[q];
        const unsigned Sincl = s + add;
        const unsigned r1 = (unsigned)(r + 1);
        if (Sincl >= r1 && Sincl - a < r1) { res[0] = 2 * tid; res[1] = r - (int)(Sincl - a); }
        if (Sincl - a >= r1 && Sincl - sv < r1) { res[0] = 2 * tid + 1; res[1] = r - (int)(Sincl - sv); }
        __syncthreads();
    }
    const unsigned P22 = (((unsigned)0) | ((cd ? 0u : 0u))) | ((unsigned)res[0]) | ((hist[b * 1024] & 0u));
    // NOTE: res[0] here is the 11-bit level-1 digit; combine with B1 extracted from any candidate's top bits
    const unsigned B1 = n > 0 ? (cd[0] >> 21) : 0u;       // all candidates share B1
    const unsigned P22full = (B1 << 11) | (unsigned)res[0];
    r = res[1];
    __syncthreads();

    // level 2: bits[9:0] among P22 candidates
    h[tid] = 0;
    __syncthreads();
    for (int i = tid; i < n; i += 1024) {
        const unsigned u = cd[i];
        if ((u >> 10) == P22full) atomicAdd(&h[u & 1023u], 1u);
    }
    __syncthreads();
    {
        const unsigned a = h[tid];
        unsigned s = a;
        #pragma unroll
        for (int d = 1; d < 64; d <<= 1) { const unsigned t = __shfl_down(s, d, 64); if (lane + d < 64) s += t; }
        if (lane == 0) wtot[w] = s;
        __syncthreads();
        unsigned add = 0;
        #pragma unroll
        for (int q = 0; q < 16; ++q) if (q > w) add += wtot[q];
        const unsigned Sincl = s + add;
        if (Sincl >= (unsigned)(r + 1) && Sincl - a < (unsigned)(r + 1)) { res[0] = tid; res[1] = r - (int)(Sincl - a); }
        __syncthreads();
    }
    const unsigned T = (P22full << 10) | (unsigned)res[0];
    const int eq = (int)h[res[0]];
    const int rem = res[1] + 1;

    int Istar = 0x7FFFFFFF;                               // all ties selected (common case)
    if (eq > rem) {                                       // rare: stable cutoff via full scan
        if (tid == 0) { srun = 0; sIstar = 0x7FFFFFFF; }
        __syncthreads();
        const float* v = lcpp + (size_t)b * NPRI;
        for (int chunk = 0; chunk < NPRI / 1024; ++chunk) {
            const int i = chunk * 1024 + tid;
            const bool tie = (__float_as_uint(v[i]) == T);
            const unsigned long long msk = __ballot(tie);
            if (lane == 0) wsum[w] = __popcll(msk);
            __syncthreads();
            int pre = 0, tot = 0;
            #pragma unroll
            for (int q = 0; q < 16; ++q) { const int c = wsum[q]; if (q < w) pre += c; tot += c; }
            const int myrank = srun + pre + __popcll(msk & ((1ull << lane) - 1ull));
            if (tie && myrank == rem - 1) sIstar = i;
            __syncthreads();
            if (tid == 0) srun += tot;
            __syncthreads();
            if (srun >= rem) break;                       // uniform
        }
        __syncthreads();
        Istar = sIstar;
    }
    if (tid == 0) { sel[b] = T; sel[128 + b] = (unsigned)Istar; }
}

// ---- kBCE (wide): selection predicate + BCE + finalize ----
__global__ __launch_bounds__(256) void kBCE(const float* __restrict__ lcpp,
                                            const unsigned char* __restrict__ confb,
                                            const float4* __restrict__ cnf,
                                            const unsigned* __restrict__ sel,
                                            const int* __restrict__ npos,
                                            double* __restrict__ acc,
                                            int* __restrict__ done,
                                            float* __restrict__ out) {
    const int b = blockIdx.y, tid = threadIdx.x;
    const unsigned T = sel[b];
    const int Istar = (int)sel[128 + b];
    const int e0 = (blockIdx.x * 256 + tid) * 8;
    const float4* v4 = (const float4*)(lcpp + (size_t)b * NPRI);
    const float4 va = v4[e0 / 4], vb = v4[e0 / 4 + 1];
    const uchar4 ca = *(const uchar4*)(confb + (size_t)b * NPRI + e0);
    const uchar4 cb4 = *(const uchar4*)(confb + (size_t)b * NPRI + e0 + 4);
    const float vv[8] = {va.x, va.y, va.z, va.w, vb.x, vb.y, vb.z, vb.w};
    const int cc[8] = {ca.x, ca.y, ca.z, ca.w, cb4.x, cb4.y, cb4.z, cb4.w};
    float local = 0.0f;
    #pragma unroll
    for (int e = 0; e < 8; ++e) {
        const int i = e0 + e;
        const unsigned u = __float_as_uint(vv[e]);
        const int c = cc[e];
        if (c > 0 || u > T || (u == T && i <= Istar)) {
            const float4 xx = cnf[(size_t)b * NPRI + i];
            local += bce1(xx.x, c == 0) + bce1(xx.y, c == 1) + bce1(xx.z, c == 2) + bce1(xx.w, c == 3);
        }
    }
    #pragma unroll
    for (int s = 32; s > 0; s >>= 1) local += __shfl_down(local, s, 64);
    __shared__ float sc[4];
    const int lane = tid & 63, w = tid >> 6;
    if (lane == 0) sc[w] = local;
    __syncthreads();
    __shared__ bool slast;
    if (tid == 0) {
        atomicAdd(&acc[1], (double)(sc[0] + sc[1] + sc[2] + sc[3]));
        __threadfence();
        const int old = atomicAdd(done, 1);
        slast = (old == 16 * BATCH - 1);
    }
    __syncthreads();
    if (slast && tid == 0) {
        __threadfence();
        int n = 0;
        for (int q = 0; q < BATCH; ++q) n += npos[q];
        const double a0 = atomicAdd(&acc[0], 0.0);        // atomic-RMW read: cross-XCD safe
        const double a1 = atomicAdd(&acc[1], 0.0);
        const double a2 = atomicAdd(&acc[2], 0.0);
        const double N = (double)n;
        out[0] = (float)(a0 / N);
        out[1] = (float)(a1 / N);
        out[2] = (float)(a2 / N);
    }
}

extern "C" void kernel_launch(void* const* d_in, const int* in_sizes, int n_in,
                              void* d_out, int out_size, void* d_ws, size_t ws_size,
                              hipStream_t stream) {
    const float* loc = (const float*)d_in[0];
    const float* cnfp = (const float*)d_in[1];
    const float* regp = (const float*)d_in[2];
    const float* tgt = (const float*)d_in[3];
    const float* pri = (const float*)d_in[4];

    char* ws = (char*)d_ws;
    double* acc = (double*)(ws + OFF_ACC);
    int* done = (int*)(ws + OFF_DONE);
    int* npos = (int*)(ws + OFF_NPOS);
    int* cnt = (int*)(ws + OFF_CNT);
    unsigned long long* bpk = (unsigned long long*)(ws + OFF_BPK);
    unsigned* sel = (unsigned*)(ws + OFF_SEL);
    unsigned* hist = (unsigned*)(ws + OFF_HIST);
    unsigned* match = (unsigned*)(ws + OFF_MATCH);
    unsigned* cand = (unsigned*)(ws + OFF_CAND);
    float* lcpp = (float*)(ws + OFF_LCPP);
    unsigned char* confb = (unsigned char*)(ws + OFF_CONF);

    hipMemsetAsync(ws, 0, HDR_BYTES, stream);   // acc/done/npos/cnt/bpk/sel (hist zeroed in kMatch)

    kMatch<<<dim3(20, BATCH), 256, 0, stream>>>(tgt, (const float4*)pri, bpk, match, hist);
    kB<<<dim3(16, BATCH), 256, 0, stream>>>(tgt, (const float4*)pri, (const float2*)loc,
                                            (const float4*)cnfp, regp, bpk, match,
                                            lcpp, confb, hist, acc, npos);
    kR2<<<dim3(8, BATCH), 256, 0, stream>>>(lcpp, hist, npos, cand, cnt);
    kR3<<<BATCH, 1024, 0, stream>>>(lcpp, hist, npos, cand, cnt, sel);
    kBCE<<<dim3(16, BATCH), 256, 0, stream>>>(lcpp, confb, (const float4*)cnfp, sel, npos,
                                              acc, done, (float*)d_out);
}